// Round 3
// baseline (614.050 us; speedup 1.0000x reference)
//
#include <hip/hip_runtime.h>

#define N_NODES 100000
#define N_EDGES 1600000
#define D_IN    128
#define D_OUT   64

#define SCAN1_BLOCKS 391        // ceil(100000/256)
typedef unsigned long long ull;

// ---------------------------------------------------------------------------
// Kernel A: support = X @ W (fp32). W column held in 128 VGPRs per thread.
// block 256 = 4 waves; wave handles one row per iteration (grid-stride).
// x row read as wave-uniform float4 broadcasts (1 line per 4 loads, L1-hit).
// ---------------------------------------------------------------------------
__global__ __launch_bounds__(256) void gcn_gemm(
    const float* __restrict__ x,        // [N, 128]
    const float* __restrict__ w,        // [128, 64]
    float* __restrict__ support)        // [N, 64]
{
    const int col  = threadIdx.x & 63;
    const int wave = threadIdx.x >> 6;

    float wreg[D_IN];
#pragma unroll
    for (int k = 0; k < D_IN; ++k)
        wreg[k] = w[k * D_OUT + col];   // coalesced across lanes

    const int stride = gridDim.x * 4;
    for (int row = blockIdx.x * 4 + wave; row < N_NODES; row += stride) {
        const float4* xr = (const float4*)(x + (size_t)row * D_IN);
        float acc = 0.f;
#pragma unroll
        for (int k4 = 0; k4 < D_IN / 4; ++k4) {
            const float4 xv = xr[k4];   // wave-uniform broadcast
            acc = fmaf(xv.x, wreg[k4 * 4 + 0], acc);
            acc = fmaf(xv.y, wreg[k4 * 4 + 1], acc);
            acc = fmaf(xv.z, wreg[k4 * 4 + 2], acc);
            acc = fmaf(xv.w, wreg[k4 * 4 + 3], acc);
        }
        support[(size_t)row * D_OUT + col] = acc;
    }
}

// ---------------------------------------------------------------------------
// CSR build, every call (ws re-poisoned each replay).
// ---------------------------------------------------------------------------
__global__ __launch_bounds__(256) void k_hist(
    const int* __restrict__ rows, int* __restrict__ counts)
{
    const int e = blockIdx.x * 256 + threadIdx.x;   // grid exact: E%256==0
    atomicAdd(&counts[rows[e]], 1);
}

// phase 1: per-block exclusive scan of counts -> offsets, block totals -> bsum
__global__ __launch_bounds__(256) void k_scan1(
    const int* __restrict__ counts, int* __restrict__ offsets,
    int* __restrict__ bsum)
{
    __shared__ int s[256];
    const int t = threadIdx.x;
    const int i = blockIdx.x * 256 + t;
    const int v = (i < N_NODES) ? counts[i] : 0;
    s[t] = v;
    __syncthreads();
#pragma unroll
    for (int off = 1; off < 256; off <<= 1) {
        const int add = (t >= off) ? s[t - off] : 0;
        __syncthreads();
        s[t] += add;
        __syncthreads();
    }
    if (i < N_NODES) offsets[i] = s[t] - v;          // exclusive
    if (t == 255) bsum[blockIdx.x] = s[255];
}

// phase 2: exclusive scan of 391 block sums (single block of 512)
__global__ __launch_bounds__(512) void k_scan2(int* __restrict__ bsum)
{
    __shared__ int s[512];
    const int t = threadIdx.x;
    const int v = (t < SCAN1_BLOCKS) ? bsum[t] : 0;
    s[t] = v;
    __syncthreads();
#pragma unroll
    for (int off = 1; off < 512; off <<= 1) {
        const int add = (t >= off) ? s[t - off] : 0;
        __syncthreads();
        s[t] += add;
        __syncthreads();
    }
    if (t < SCAN1_BLOCKS) bsum[t] = s[t] - v;        // exclusive
}

// phase 3: add block base; duplicate into cursor
__global__ __launch_bounds__(256) void k_scan3(
    int* __restrict__ offsets, const int* __restrict__ bsum,
    int* __restrict__ cursor)
{
    const int i = blockIdx.x * 256 + threadIdx.x;
    if (i < N_NODES) {
        const int o = offsets[i] + bsum[blockIdx.x];
        offsets[i] = o;
        cursor[i]  = o;
    }
}

// place each edge's (col, val) into CSR slot
__global__ __launch_bounds__(256) void k_place(
    const int* __restrict__ rows, const int* __restrict__ cols,
    const float* __restrict__ vals, int* __restrict__ cursor,
    ull* __restrict__ pairs)
{
    const int e = blockIdx.x * 256 + threadIdx.x;
    const int r = rows[e];
    const int pos = atomicAdd(&cursor[r], 1);
    const ull p = ((ull)__float_as_uint(vals[e]) << 32) | (unsigned)cols[e];
    pairs[pos] = p;
}

// ---------------------------------------------------------------------------
// Segmented row sum + fused PReLU. One wave per row, lane = column.
// 4-wide unroll -> 4 independent 256B gathers in flight per wave.
// ---------------------------------------------------------------------------
__global__ __launch_bounds__(256) void k_rowsum(
    const int* __restrict__ offsets, const int* __restrict__ counts,
    const ull* __restrict__ pairs, const float* __restrict__ support,
    const float* __restrict__ prelu_a, float* __restrict__ out)
{
    const int lane = threadIdx.x & 63;
    const int row  = blockIdx.x * 4 + (threadIdx.x >> 6);  // grid exact: N%4==0

    const int start = offsets[row];
    const int deg   = counts[row];

    float acc = 0.f;
    int j = 0;
    for (; j + 4 <= deg; j += 4) {
        const ull p0 = pairs[start + j + 0];
        const ull p1 = pairs[start + j + 1];
        const ull p2 = pairs[start + j + 2];
        const ull p3 = pairs[start + j + 3];
        const float s0 = support[(size_t)(unsigned)(p0 & 0xffffffffu) * D_OUT + lane];
        const float s1 = support[(size_t)(unsigned)(p1 & 0xffffffffu) * D_OUT + lane];
        const float s2 = support[(size_t)(unsigned)(p2 & 0xffffffffu) * D_OUT + lane];
        const float s3 = support[(size_t)(unsigned)(p3 & 0xffffffffu) * D_OUT + lane];
        acc = fmaf(__uint_as_float((unsigned)(p0 >> 32)), s0, acc);
        acc = fmaf(__uint_as_float((unsigned)(p1 >> 32)), s1, acc);
        acc = fmaf(__uint_as_float((unsigned)(p2 >> 32)), s2, acc);
        acc = fmaf(__uint_as_float((unsigned)(p3 >> 32)), s3, acc);
    }
    for (; j < deg; ++j) {
        const ull p = pairs[start + j];
        const float s = support[(size_t)(unsigned)(p & 0xffffffffu) * D_OUT + lane];
        acc = fmaf(__uint_as_float((unsigned)(p >> 32)), s, acc);
    }

    const float a = prelu_a[0];
    out[(size_t)row * D_OUT + lane] = acc > 0.f ? acc : a * acc;
}

// ---------------------------------------------------------------------------
extern "C" void kernel_launch(void* const* d_in, const int* in_sizes, int n_in,
                              void* d_out, int out_size, void* d_ws, size_t ws_size,
                              hipStream_t stream) {
    const float* x    = (const float*)d_in[0];
    const int*   rows = (const int*)d_in[1];
    const int*   cols = (const int*)d_in[2];
    const float* vals = (const float*)d_in[3];
    const float* w    = (const float*)d_in[4];
    const float* pa   = (const float*)d_in[5];

    float* out     = (float*)d_out;                    // [N*64] PReLU output
    float* support = out + (size_t)N_NODES * D_OUT;    // [N*64] support (tuple elem 1)

    // workspace layout (~14 MB)
    int* counts  = (int*)d_ws;             // 100000 (pad to 100032)
    int* offsets = counts  + 100032;
    int* cursor  = offsets + 100032;
    int* bsum    = cursor  + 100032;       // 512
    ull* pairs   = (ull*)(bsum + 512);     // 1.6M x 8B (offset 8B-aligned)

    hipMemsetAsync(counts, 0, 100032 * sizeof(int), stream);

    gcn_gemm<<<512, 256, 0, stream>>>(x, w, support);
    k_hist  <<<N_EDGES / 256, 256, 0, stream>>>(rows, counts);
    k_scan1 <<<SCAN1_BLOCKS, 256, 0, stream>>>(counts, offsets, bsum);
    k_scan2 <<<1, 512, 0, stream>>>(bsum);
    k_scan3 <<<SCAN1_BLOCKS, 256, 0, stream>>>(offsets, bsum, cursor);
    k_place <<<N_EDGES / 256, 256, 0, stream>>>(rows, cols, vals, cursor, pairs);
    k_rowsum<<<N_NODES / 4, 256, 0, stream>>>(offsets, counts, pairs, support, pa, out);
}

// Round 4
// 401.175 us; speedup vs baseline: 1.5306x; 1.5306x over previous
//
#include <hip/hip_runtime.h>

#define N_NODES 100000
#define N_EDGES 1600000
#define D_IN    128
#define D_OUT   64

#define SCAN1_BLOCKS 391        // ceil(100000/256)
#define XT_STRIDE 260           // padded row-count stride: 16B-aligned, low conflicts
typedef unsigned long long ull;

// ---------------------------------------------------------------------------
// Kernel A: support = X @ W (fp32). Register-tiled LDS GEMM.
// Block = 256 threads -> 256 rows x 64 cols, 8x8 per thread.
// Per k: 4 ds_read_b128 per 64 FMAs. LDS 66 KB -> 2 blocks/CU.
// ---------------------------------------------------------------------------
__global__ __launch_bounds__(256) void gcn_gemm(
    const float* __restrict__ x,        // [N, 128]
    const float* __restrict__ w,        // [128, 64]
    float* __restrict__ support)        // [N, 64]
{
    __shared__ float wl[D_IN * D_OUT];      // [k][col], 32 KB
    __shared__ float xT[32 * XT_STRIDE];    // [k_local][row], 33.3 KB

    const int t  = threadIdx.x;
    const int tx = t & 7;                   // col group: cols tx*8 .. tx*8+7
    const int ty = t >> 3;                  // row group: rows ty*8 .. ty*8+7 (0..31)
    const long row0 = (long)blockIdx.x * 256;

    // stage full W once (coalesced float4)
    {
        const float4* wf  = (const float4*)w;
        float4*       wlf = (float4*)wl;
#pragma unroll
        for (int j = 0; j < 8; ++j)
            wlf[t + 256 * j] = wf[t + 256 * j];
    }

    float acc[8][8];
#pragma unroll
    for (int i = 0; i < 8; ++i)
#pragma unroll
        for (int j = 0; j < 8; ++j)
            acc[i][j] = 0.f;

    for (int kc = 0; kc < 4; ++kc) {
        const int k0 = kc * 32;
        __syncthreads();                    // xT readers from prev chunk done

        // stage x chunk transposed: rows row0..row0+255, k in [k0, k0+32)
        const int kk = tx * 4;              // local k base 0,4,...,28
#pragma unroll
        for (int it = 0; it < 8; ++it) {
            const int  rg   = it * 32 + ty; // 0..255
            const long grow = row0 + rg;
            float4 v = make_float4(0.f, 0.f, 0.f, 0.f);
            if (grow < N_NODES)
                v = *(const float4*)&x[grow * D_IN + k0 + kk];
            xT[(kk + 0) * XT_STRIDE + rg] = v.x;
            xT[(kk + 1) * XT_STRIDE + rg] = v.y;
            xT[(kk + 2) * XT_STRIDE + rg] = v.z;
            xT[(kk + 3) * XT_STRIDE + rg] = v.w;
        }
        __syncthreads();

#pragma unroll 8
        for (int k = 0; k < 32; ++k) {
            const float4 a0 = *(const float4*)&xT[k * XT_STRIDE + ty * 8];
            const float4 a1 = *(const float4*)&xT[k * XT_STRIDE + ty * 8 + 4];
            const float4 b0 = *(const float4*)&wl[(k0 + k) * D_OUT + tx * 8];
            const float4 b1 = *(const float4*)&wl[(k0 + k) * D_OUT + tx * 8 + 4];
            const float av[8] = {a0.x, a0.y, a0.z, a0.w, a1.x, a1.y, a1.z, a1.w};
            const float bv[8] = {b0.x, b0.y, b0.z, b0.w, b1.x, b1.y, b1.z, b1.w};
#pragma unroll
            for (int i = 0; i < 8; ++i)
#pragma unroll
                for (int j = 0; j < 8; ++j)
                    acc[i][j] = fmaf(av[i], bv[j], acc[i][j]);
        }
    }

    // store 8 rows x 8 cols per thread (2 x float4 per row)
#pragma unroll
    for (int i = 0; i < 8; ++i) {
        const long r = row0 + ty * 8 + i;
        if (r < N_NODES) {
            float4 o0 = make_float4(acc[i][0], acc[i][1], acc[i][2], acc[i][3]);
            float4 o1 = make_float4(acc[i][4], acc[i][5], acc[i][6], acc[i][7]);
            *(float4*)&support[r * D_OUT + tx * 8]     = o0;
            *(float4*)&support[r * D_OUT + tx * 8 + 4] = o1;
        }
    }
}

// ---------------------------------------------------------------------------
// CSR build, every call (ws re-poisoned each replay).
// ---------------------------------------------------------------------------
__global__ __launch_bounds__(256) void k_hist(
    const int* __restrict__ rows, int* __restrict__ counts)
{
    const int e = blockIdx.x * 256 + threadIdx.x;   // grid exact: E%256==0
    atomicAdd(&counts[rows[e]], 1);
}

// phase 1: per-block exclusive scan of counts -> offsets, block totals -> bsum
__global__ __launch_bounds__(256) void k_scan1(
    const int* __restrict__ counts, int* __restrict__ offsets,
    int* __restrict__ bsum)
{
    __shared__ int s[256];
    const int t = threadIdx.x;
    const int i = blockIdx.x * 256 + t;
    const int v = (i < N_NODES) ? counts[i] : 0;
    s[t] = v;
    __syncthreads();
#pragma unroll
    for (int off = 1; off < 256; off <<= 1) {
        const int add = (t >= off) ? s[t - off] : 0;
        __syncthreads();
        s[t] += add;
        __syncthreads();
    }
    if (i < N_NODES) offsets[i] = s[t] - v;          // exclusive
    if (t == 255) bsum[blockIdx.x] = s[255];
}

// phase 2: exclusive scan of 391 block sums (single block of 512)
__global__ __launch_bounds__(512) void k_scan2(int* __restrict__ bsum)
{
    __shared__ int s[512];
    const int t = threadIdx.x;
    const int v = (t < SCAN1_BLOCKS) ? bsum[t] : 0;
    s[t] = v;
    __syncthreads();
#pragma unroll
    for (int off = 1; off < 512; off <<= 1) {
        const int add = (t >= off) ? s[t - off] : 0;
        __syncthreads();
        s[t] += add;
        __syncthreads();
    }
    if (t < SCAN1_BLOCKS) bsum[t] = s[t] - v;        // exclusive
}

// phase 3: add block base; duplicate into cursor
__global__ __launch_bounds__(256) void k_scan3(
    int* __restrict__ offsets, const int* __restrict__ bsum,
    int* __restrict__ cursor)
{
    const int i = blockIdx.x * 256 + threadIdx.x;
    if (i < N_NODES) {
        const int o = offsets[i] + bsum[blockIdx.x];
        offsets[i] = o;
        cursor[i]  = o;
    }
}

// place each edge's (col, val) into CSR slot
__global__ __launch_bounds__(256) void k_place(
    const int* __restrict__ rows, const int* __restrict__ cols,
    const float* __restrict__ vals, int* __restrict__ cursor,
    ull* __restrict__ pairs)
{
    const int e = blockIdx.x * 256 + threadIdx.x;
    const int r = rows[e];
    const int pos = atomicAdd(&cursor[r], 1);
    const ull p = ((ull)__float_as_uint(vals[e]) << 32) | (unsigned)cols[e];
    pairs[pos] = p;
}

// ---------------------------------------------------------------------------
// Segmented row sum + fused PReLU. One wave per row, lane = column.
// ---------------------------------------------------------------------------
__global__ __launch_bounds__(256) void k_rowsum(
    const int* __restrict__ offsets, const int* __restrict__ counts,
    const ull* __restrict__ pairs, const float* __restrict__ support,
    const float* __restrict__ prelu_a, float* __restrict__ out)
{
    const int lane = threadIdx.x & 63;
    const int row  = blockIdx.x * 4 + (threadIdx.x >> 6);  // grid exact: N%4==0

    const int start = offsets[row];
    const int deg   = counts[row];

    float acc = 0.f;
    int j = 0;
    for (; j + 4 <= deg; j += 4) {
        const ull p0 = pairs[start + j + 0];
        const ull p1 = pairs[start + j + 1];
        const ull p2 = pairs[start + j + 2];
        const ull p3 = pairs[start + j + 3];
        const float s0 = support[(size_t)(unsigned)(p0 & 0xffffffffu) * D_OUT + lane];
        const float s1 = support[(size_t)(unsigned)(p1 & 0xffffffffu) * D_OUT + lane];
        const float s2 = support[(size_t)(unsigned)(p2 & 0xffffffffu) * D_OUT + lane];
        const float s3 = support[(size_t)(unsigned)(p3 & 0xffffffffu) * D_OUT + lane];
        acc = fmaf(__uint_as_float((unsigned)(p0 >> 32)), s0, acc);
        acc = fmaf(__uint_as_float((unsigned)(p1 >> 32)), s1, acc);
        acc = fmaf(__uint_as_float((unsigned)(p2 >> 32)), s2, acc);
        acc = fmaf(__uint_as_float((unsigned)(p3 >> 32)), s3, acc);
    }
    for (; j < deg; ++j) {
        const ull p = pairs[start + j];
        const float s = support[(size_t)(unsigned)(p & 0xffffffffu) * D_OUT + lane];
        acc = fmaf(__uint_as_float((unsigned)(p >> 32)), s, acc);
    }

    const float a = prelu_a[0];
    out[(size_t)row * D_OUT + lane] = acc > 0.f ? acc : a * acc;
}

// ---------------------------------------------------------------------------
extern "C" void kernel_launch(void* const* d_in, const int* in_sizes, int n_in,
                              void* d_out, int out_size, void* d_ws, size_t ws_size,
                              hipStream_t stream) {
    const float* x    = (const float*)d_in[0];
    const int*   rows = (const int*)d_in[1];
    const int*   cols = (const int*)d_in[2];
    const float* vals = (const float*)d_in[3];
    const float* w    = (const float*)d_in[4];
    const float* pa   = (const float*)d_in[5];

    float* out     = (float*)d_out;                    // [N*64] PReLU output
    float* support = out + (size_t)N_NODES * D_OUT;    // [N*64] support (tuple elem 1)

    // workspace layout (~14 MB)
    int* counts  = (int*)d_ws;             // 100000 (pad to 100032)
    int* offsets = counts  + 100032;
    int* cursor  = offsets + 100032;
    int* bsum    = cursor  + 100032;       // 512
    ull* pairs   = (ull*)(bsum + 512);     // 1.6M x 8B (offset 8B-aligned)

    hipMemsetAsync(counts, 0, 100032 * sizeof(int), stream);

    gcn_gemm<<<(N_NODES + 255) / 256, 256, 0, stream>>>(x, w, support);
    k_hist  <<<N_EDGES / 256, 256, 0, stream>>>(rows, counts);
    k_scan1 <<<SCAN1_BLOCKS, 256, 0, stream>>>(counts, offsets, bsum);
    k_scan2 <<<1, 512, 0, stream>>>(bsum);
    k_scan3 <<<SCAN1_BLOCKS, 256, 0, stream>>>(offsets, bsum, cursor);
    k_place <<<N_EDGES / 256, 256, 0, stream>>>(rows, cols, vals, cursor, pairs);
    k_rowsum<<<N_NODES / 4, 256, 0, stream>>>(offsets, counts, pairs, support, pa, out);
}

// Round 5
// 350.477 us; speedup vs baseline: 1.7520x; 1.1447x over previous
//
#include <hip/hip_runtime.h>

#define N_NODES 100000
#define N_EDGES 1600000
#define D_IN    128
#define D_OUT   64

#define SCAN1_BLOCKS 391        // ceil(100000/256)
#define XT_STRIDE 260           // padded row-count stride: 16B-aligned, low conflicts
#define ROWS_PER_GROUP 12500    // 8 groups of 12500 rows
#define PLACE_BLOCKS 2048       // 256 blocks per group
typedef unsigned long long ull;

// ---------------------------------------------------------------------------
// Kernel A: support = X @ W (fp32). Register-tiled LDS GEMM.
// Block = 256 threads -> 256 rows x 64 cols, 8x8 per thread.
// ---------------------------------------------------------------------------
__global__ __launch_bounds__(256) void gcn_gemm(
    const float* __restrict__ x,        // [N, 128]
    const float* __restrict__ w,        // [128, 64]
    float* __restrict__ support)        // [N, 64]
{
    __shared__ float wl[D_IN * D_OUT];      // [k][col], 32 KB
    __shared__ float xT[32 * XT_STRIDE];    // [k_local][row], 33.3 KB

    const int t  = threadIdx.x;
    const int tx = t & 7;                   // col group: cols tx*8 .. tx*8+7
    const int ty = t >> 3;                  // row group: rows ty*8 .. ty*8+7 (0..31)
    const long row0 = (long)blockIdx.x * 256;

    // stage full W once (coalesced float4)
    {
        const float4* wf  = (const float4*)w;
        float4*       wlf = (float4*)wl;
#pragma unroll
        for (int j = 0; j < 8; ++j)
            wlf[t + 256 * j] = wf[t + 256 * j];
    }

    float acc[8][8];
#pragma unroll
    for (int i = 0; i < 8; ++i)
#pragma unroll
        for (int j = 0; j < 8; ++j)
            acc[i][j] = 0.f;

    for (int kc = 0; kc < 4; ++kc) {
        const int k0 = kc * 32;
        __syncthreads();                    // xT readers from prev chunk done

        // stage x chunk transposed: rows row0..row0+255, k in [k0, k0+32)
        const int kk = tx * 4;              // local k base 0,4,...,28
#pragma unroll
        for (int it = 0; it < 8; ++it) {
            const int  rg   = it * 32 + ty; // 0..255
            const long grow = row0 + rg;
            float4 v = make_float4(0.f, 0.f, 0.f, 0.f);
            if (grow < N_NODES)
                v = *(const float4*)&x[grow * D_IN + k0 + kk];
            xT[(kk + 0) * XT_STRIDE + rg] = v.x;
            xT[(kk + 1) * XT_STRIDE + rg] = v.y;
            xT[(kk + 2) * XT_STRIDE + rg] = v.z;
            xT[(kk + 3) * XT_STRIDE + rg] = v.w;
        }
        __syncthreads();

#pragma unroll 8
        for (int k = 0; k < 32; ++k) {
            const float4 a0 = *(const float4*)&xT[k * XT_STRIDE + ty * 8];
            const float4 a1 = *(const float4*)&xT[k * XT_STRIDE + ty * 8 + 4];
            const float4 b0 = *(const float4*)&wl[(k0 + k) * D_OUT + tx * 8];
            const float4 b1 = *(const float4*)&wl[(k0 + k) * D_OUT + tx * 8 + 4];
            const float av[8] = {a0.x, a0.y, a0.z, a0.w, a1.x, a1.y, a1.z, a1.w};
            const float bv[8] = {b0.x, b0.y, b0.z, b0.w, b1.x, b1.y, b1.z, b1.w};
#pragma unroll
            for (int i = 0; i < 8; ++i)
#pragma unroll
                for (int j = 0; j < 8; ++j)
                    acc[i][j] = fmaf(av[i], bv[j], acc[i][j]);
        }
    }

    // store 8 rows x 8 cols per thread (2 x float4 per row)
#pragma unroll
    for (int i = 0; i < 8; ++i) {
        const long r = row0 + ty * 8 + i;
        if (r < N_NODES) {
            float4 o0 = make_float4(acc[i][0], acc[i][1], acc[i][2], acc[i][3]);
            float4 o1 = make_float4(acc[i][4], acc[i][5], acc[i][6], acc[i][7]);
            *(float4*)&support[r * D_OUT + tx * 8]     = o0;
            *(float4*)&support[r * D_OUT + tx * 8 + 4] = o1;
        }
    }
}

// ---------------------------------------------------------------------------
// CSR build, every call (ws re-poisoned each replay).
// ---------------------------------------------------------------------------
__global__ __launch_bounds__(256) void k_hist(
    const int* __restrict__ rows, int* __restrict__ counts)
{
    const int e = blockIdx.x * 256 + threadIdx.x;   // grid exact: E%256==0
    atomicAdd(&counts[rows[e]], 1);
}

// phase 1: per-block exclusive scan of counts -> offsets, block totals -> bsum
__global__ __launch_bounds__(256) void k_scan1(
    const int* __restrict__ counts, int* __restrict__ offsets,
    int* __restrict__ bsum)
{
    __shared__ int s[256];
    const int t = threadIdx.x;
    const int i = blockIdx.x * 256 + t;
    const int v = (i < N_NODES) ? counts[i] : 0;
    s[t] = v;
    __syncthreads();
#pragma unroll
    for (int off = 1; off < 256; off <<= 1) {
        const int add = (t >= off) ? s[t - off] : 0;
        __syncthreads();
        s[t] += add;
        __syncthreads();
    }
    if (i < N_NODES) offsets[i] = s[t] - v;          // exclusive
    if (t == 255) bsum[blockIdx.x] = s[255];
}

// phase 2: exclusive scan of 391 block sums (single block of 512)
__global__ __launch_bounds__(512) void k_scan2(int* __restrict__ bsum)
{
    __shared__ int s[512];
    const int t = threadIdx.x;
    const int v = (t < SCAN1_BLOCKS) ? bsum[t] : 0;
    s[t] = v;
    __syncthreads();
#pragma unroll
    for (int off = 1; off < 512; off <<= 1) {
        const int add = (t >= off) ? s[t - off] : 0;
        __syncthreads();
        s[t] += add;
        __syncthreads();
    }
    if (t < SCAN1_BLOCKS) bsum[t] = s[t] - v;        // exclusive
}

// phase 3: add block base; duplicate into cursor
__global__ __launch_bounds__(256) void k_scan3(
    int* __restrict__ offsets, const int* __restrict__ bsum,
    int* __restrict__ cursor)
{
    const int i = blockIdx.x * 256 + threadIdx.x;
    if (i < N_NODES) {
        const int o = offsets[i] + bsum[blockIdx.x];
        offsets[i] = o;
        cursor[i]  = o;
    }
}

// ---------------------------------------------------------------------------
// Place, row-range partitioned for XCD-local writes.
// group g = blockIdx & 7 (round-robin -> one XCD per group) handles rows
// [g*12500, (g+1)*12500); its CSR slice is a contiguous ~1.6 MB region, so
// pair-lines are fully assembled in ONE L2 before writeback (kills the 8x
// partial-line writeback amplification: WRITE_SIZE 100 MB -> ~16 MB).
// Every block scans a strided slice of all edges and filters by row range.
// ---------------------------------------------------------------------------
__global__ __launch_bounds__(256) void k_place(
    const int* __restrict__ rows, const int* __restrict__ cols,
    const float* __restrict__ vals, int* __restrict__ cursor,
    ull* __restrict__ pairs)
{
    const int g   = blockIdx.x & 7;
    const int b   = blockIdx.x >> 3;
    const int nb  = gridDim.x >> 3;
    const int rlo = g * ROWS_PER_GROUP;
    const int rhi = rlo + ROWS_PER_GROUP;

    for (int base = b * 256; base < N_EDGES; base += nb * 256) {
        const int e = base + threadIdx.x;           // E%256==0 -> in bounds
        const int r = rows[e];
        if (r >= rlo && r < rhi) {
            const int pos = atomicAdd(&cursor[r], 1);
            pairs[pos] = ((ull)__float_as_uint(vals[e]) << 32) | (unsigned)cols[e];
        }
    }
}

// ---------------------------------------------------------------------------
// Segmented row sum + fused PReLU. One wave per row, lane = column.
// 8-wide unroll -> 8 independent 256B gathers in flight per wave.
// ---------------------------------------------------------------------------
__global__ __launch_bounds__(256) void k_rowsum(
    const int* __restrict__ offsets, const int* __restrict__ counts,
    const ull* __restrict__ pairs, const float* __restrict__ support,
    const float* __restrict__ prelu_a, float* __restrict__ out)
{
    const int lane = threadIdx.x & 63;
    const int row  = blockIdx.x * 4 + (threadIdx.x >> 6);  // grid exact: N%4==0

    const int start = offsets[row];
    const int deg   = counts[row];

    float acc = 0.f;
    int j = 0;
    for (; j + 8 <= deg; j += 8) {
        ull p[8];
#pragma unroll
        for (int u = 0; u < 8; ++u) p[u] = pairs[start + j + u];
        float s[8];
#pragma unroll
        for (int u = 0; u < 8; ++u)
            s[u] = support[(size_t)(unsigned)(p[u] & 0xffffffffu) * D_OUT + lane];
#pragma unroll
        for (int u = 0; u < 8; ++u)
            acc = fmaf(__uint_as_float((unsigned)(p[u] >> 32)), s[u], acc);
    }
    for (; j + 4 <= deg; j += 4) {
        ull p[4];
#pragma unroll
        for (int u = 0; u < 4; ++u) p[u] = pairs[start + j + u];
        float s[4];
#pragma unroll
        for (int u = 0; u < 4; ++u)
            s[u] = support[(size_t)(unsigned)(p[u] & 0xffffffffu) * D_OUT + lane];
#pragma unroll
        for (int u = 0; u < 4; ++u)
            acc = fmaf(__uint_as_float((unsigned)(p[u] >> 32)), s[u], acc);
    }
    for (; j < deg; ++j) {
        const ull p = pairs[start + j];
        const float s = support[(size_t)(unsigned)(p & 0xffffffffu) * D_OUT + lane];
        acc = fmaf(__uint_as_float((unsigned)(p >> 32)), s, acc);
    }

    const float a = prelu_a[0];
    out[(size_t)row * D_OUT + lane] = acc > 0.f ? acc : a * acc;
}

// ---------------------------------------------------------------------------
extern "C" void kernel_launch(void* const* d_in, const int* in_sizes, int n_in,
                              void* d_out, int out_size, void* d_ws, size_t ws_size,
                              hipStream_t stream) {
    const float* x    = (const float*)d_in[0];
    const int*   rows = (const int*)d_in[1];
    const int*   cols = (const int*)d_in[2];
    const float* vals = (const float*)d_in[3];
    const float* w    = (const float*)d_in[4];
    const float* pa   = (const float*)d_in[5];

    float* out     = (float*)d_out;                    // [N*64] PReLU output
    float* support = out + (size_t)N_NODES * D_OUT;    // [N*64] support (tuple elem 1)

    // workspace layout (~14 MB)
    int* counts  = (int*)d_ws;             // 100000 (pad to 100032)
    int* offsets = counts  + 100032;
    int* cursor  = offsets + 100032;
    int* bsum    = cursor  + 100032;       // 512
    ull* pairs   = (ull*)(bsum + 512);     // 1.6M x 8B (offset 8B-aligned)

    hipMemsetAsync(counts, 0, 100032 * sizeof(int), stream);

    gcn_gemm<<<(N_NODES + 255) / 256, 256, 0, stream>>>(x, w, support);
    k_hist  <<<N_EDGES / 256, 256, 0, stream>>>(rows, counts);
    k_scan1 <<<SCAN1_BLOCKS, 256, 0, stream>>>(counts, offsets, bsum);
    k_scan2 <<<1, 512, 0, stream>>>(bsum);
    k_scan3 <<<SCAN1_BLOCKS, 256, 0, stream>>>(offsets, bsum, cursor);
    k_place <<<PLACE_BLOCKS, 256, 0, stream>>>(rows, cols, vals, cursor, pairs);
    k_rowsum<<<N_NODES / 4, 256, 0, stream>>>(offsets, counts, pairs, support, pa, out);
}